// Round 1
// 67.406 us; speedup vs baseline: 1.0215x; 1.0215x over previous
//
#include <hip/hip_runtime.h>

// RBF network, SEPARABLE-GRID form — SINGLE FUSED KERNEL, SMEM weights.
//
// Round-12: the R11 kernel's weight path was 125 uniform ds_read_b128 per
// wave (25 rows x 5). A broadcast b128 still returns 64x16B=1KB to the RF,
// ~10 cyc each, and the LDS pipe is per-CU: 16 waves x 125 x ~10cyc ~= 8us
// of serialized LDS traffic per CU -- the dominant kernel cost (VALU floor
// is only ~1.7us). Weights are wave-uniform -> move them to the SCALAR pipe.
//
// Re-slice waves over i (wave w owns i in [5w,5w+5)) instead of k: each
// wave's 25 weight rows (i,j) are then CONTIGUOUS 80B runs of lin_w in its
// ORIGINAL layout (c = i*100 + j*20 + k). One s_load_dwordx16 + s_load_dwordx4
// per row, v_pk_fma_f32 reads the weight pair straight from aligned SGPRs.
// Deletes: 9.6KB wlds, the 8KB/block transpose read (+bank-conflicted LDS
// writes), and all weight LDS traffic. SMEM path: 50 s_loads/wave, lin_w
// (8KB) fully sK$-resident. lgkmcnt(0) per row (SMEM completes out-of-order,
// partial waits unsafe); 4 waves/SIMD hide the sK$ latency.
//
//   num = sum_i e_i * sum_j f_j * dot20(w[i*100+j*20 .. +20), g[0..20))
//   den = (sum_i e_i)(sum_j f_j)(sum_k g_k)     (common exp factor cancels)
// Cross-wave reduce carries (num, partial sum_e) per point.

typedef float v2f  __attribute__((ext_vector_type(2)));
typedef float v4f  __attribute__((ext_vector_type(4)));
typedef float v16f __attribute__((ext_vector_type(16)));

__device__ __forceinline__ v2f mk2(float lo, float hi) { v2f r; r.x = lo; r.y = hi; return r; }

template<int OFF>
__device__ __forceinline__ void sload20(const float* __restrict__ base, v16f& a, v4f& b) {
    // 20 contiguous floats at byte offset OFF (16B-aligned; SMEM needs only
    // dword alignment on gfx9+). Wait inside: SMEM returns out-of-order, so
    // lgkmcnt(0) is the only safe wait; data deps order the consumers.
    asm("s_load_dwordx16 %0, %2, %c3\n\t"
        "s_load_dwordx4  %1, %2, %c4\n\t"
        "s_waitcnt lgkmcnt(0)"
        : "=s"(a), "=s"(b)
        : "s"(base), "i"(OFF), "i"(OFF + 64));
}

__global__ __launch_bounds__(256, 4) void rbf_fused(
        const float* __restrict__ x,
        const float* __restrict__ centers,
        const float* __restrict__ beta,
        const float* __restrict__ lin_w,
        float* __restrict__ out,
        int n) {
    __shared__ float cst[90];          // k1e[20]@0 k0e@20 k1f[5]@40 k0f@45 k1g[20]@50 k0g@70
    __shared__ float red[4][4][64];    // cross-wave: numA, seA, numB, seB

    const int tid  = threadIdx.x;
    const int lane = tid & 63;
    const int wvu  = __builtin_amdgcn_readfirstlane(tid >> 6);  // 0..3, SGPR

    // --- grid-line constants from centers/beta (45 threads) ---
    if (tid < 45) {
        const float LOG2E = 1.4426950408889634f;
        float b = beta[0] * LOG2E;
        float gv;
        int k1o, k0o, idx;
        if (tid < 20)      { idx = tid;      gv = centers[3*(idx*100) + 0]; k1o = 0;  k0o = 20; }
        else if (tid < 25) { idx = tid - 20; gv = centers[3*(idx*20)  + 1]; k1o = 40; k0o = 45; }
        else               { idx = tid - 25; gv = centers[3*idx       + 2]; k1o = 50; k0o = 70; }
        cst[k1o + idx] = 2.0f * b * gv;
        cst[k0o + idx] = -b * gv * gv;
    }

    const int pA = blockIdx.x * 128 + lane;       // 128 points per block
    const int pB = pA + 64;
    const bool vA = (pA < n), vB = (pB < n);

    float a0 = 0.f, a1 = 0.f, a2 = 0.f, b0 = 0.f, b1 = 0.f, b2 = 0.f;
    if (vA) { a0 = x[3*pA]; a1 = x[3*pA+1]; a2 = x[3*pA+2]; }
    if (vB) { b0 = x[3*pB]; b1 = x[3*pB+1]; b2 = x[3*pB+2]; }

    __syncthreads();                              // cst ready

    // wave's weight base: rows i = wvu*5 .. wvu*5+4  (500 floats, contiguous)
    const float* wbase = lin_w + wvu * 500;

    // per-point factors: f_j (5) and g_k (all 20, as v2f pairs)
    float fA[5], fB[5];
    #pragma unroll
    for (int j = 0; j < 5; ++j) {
        float k1 = cst[40 + j], k0 = cst[45 + j];
        fA[j] = __builtin_amdgcn_exp2f(fmaf(k1, a1, k0));
        fB[j] = __builtin_amdgcn_exp2f(fmaf(k1, b1, k0));
    }
    v2f GA[10], GB[10];
    #pragma unroll
    for (int p = 0; p < 10; ++p) {
        float k1x = cst[50 + 2*p],     k0x = cst[70 + 2*p];
        float k1y = cst[50 + 2*p + 1], k0y = cst[70 + 2*p + 1];
        GA[p].x = __builtin_amdgcn_exp2f(fmaf(k1x, a2, k0x));
        GA[p].y = __builtin_amdgcn_exp2f(fmaf(k1y, a2, k0y));
        GB[p].x = __builtin_amdgcn_exp2f(fmaf(k1x, b2, k0x));
        GB[p].y = __builtin_amdgcn_exp2f(fmaf(k1y, b2, k0y));
    }

    float numA = 0.f, numB = 0.f, seA = 0.f, seB = 0.f;
    float uA = 0.f, uB = 0.f;

    // row R: local i = R/5, j = R%5; byte offset (R/5)*400 + (R%5)*80.
    // 10 pk-FMAs per point per row, weight pairs direct from SGPRs.
#define RBF_ROW(R) do { \
        v16f W16; v4f W4; \
        sload20<((R)/5)*400 + ((R)%5)*80>(wbase, W16, W4); \
        v2f w, tA, tB; \
        w = mk2(W16[0],  W16[1]);  tA = w * GA[0]; tB = w * GB[0]; \
        w = mk2(W16[2],  W16[3]);  tA = __builtin_elementwise_fma(w, GA[1], tA); tB = __builtin_elementwise_fma(w, GB[1], tB); \
        w = mk2(W16[4],  W16[5]);  tA = __builtin_elementwise_fma(w, GA[2], tA); tB = __builtin_elementwise_fma(w, GB[2], tB); \
        w = mk2(W16[6],  W16[7]);  tA = __builtin_elementwise_fma(w, GA[3], tA); tB = __builtin_elementwise_fma(w, GB[3], tB); \
        w = mk2(W16[8],  W16[9]);  tA = __builtin_elementwise_fma(w, GA[4], tA); tB = __builtin_elementwise_fma(w, GB[4], tB); \
        w = mk2(W16[10], W16[11]); tA = __builtin_elementwise_fma(w, GA[5], tA); tB = __builtin_elementwise_fma(w, GB[5], tB); \
        w = mk2(W16[12], W16[13]); tA = __builtin_elementwise_fma(w, GA[6], tA); tB = __builtin_elementwise_fma(w, GB[6], tB); \
        w = mk2(W16[14], W16[15]); tA = __builtin_elementwise_fma(w, GA[7], tA); tB = __builtin_elementwise_fma(w, GB[7], tB); \
        w = mk2(W4[0],   W4[1]);   tA = __builtin_elementwise_fma(w, GA[8], tA); tB = __builtin_elementwise_fma(w, GB[8], tB); \
        w = mk2(W4[2],   W4[3]);   tA = __builtin_elementwise_fma(w, GA[9], tA); tB = __builtin_elementwise_fma(w, GB[9], tB); \
        uA = fmaf(fA[(R)%5], tA.x + tA.y, uA); \
        uB = fmaf(fB[(R)%5], tB.x + tB.y, uB); \
    } while (0)

    // fold row-group ii (local i) with its e_i; reset u accumulators.
#define RBF_FOLD(II) do { \
        float k1 = cst[5*wvu + (II)], k0 = cst[20 + 5*wvu + (II)]; \
        float eAv = __builtin_amdgcn_exp2f(fmaf(k1, a0, k0)); \
        float eBv = __builtin_amdgcn_exp2f(fmaf(k1, b0, k0)); \
        numA = fmaf(eAv, uA, numA); numB = fmaf(eBv, uB, numB); \
        seA += eAv; seB += eBv; uA = 0.f; uB = 0.f; \
    } while (0)

    RBF_ROW(0);  RBF_ROW(1);  RBF_ROW(2);  RBF_ROW(3);  RBF_ROW(4);   RBF_FOLD(0);
    RBF_ROW(5);  RBF_ROW(6);  RBF_ROW(7);  RBF_ROW(8);  RBF_ROW(9);   RBF_FOLD(1);
    RBF_ROW(10); RBF_ROW(11); RBF_ROW(12); RBF_ROW(13); RBF_ROW(14);  RBF_FOLD(2);
    RBF_ROW(15); RBF_ROW(16); RBF_ROW(17); RBF_ROW(18); RBF_ROW(19);  RBF_FOLD(3);
    RBF_ROW(20); RBF_ROW(21); RBF_ROW(22); RBF_ROW(23); RBF_ROW(24);  RBF_FOLD(4);

#undef RBF_ROW
#undef RBF_FOLD

    // cross-wave reduce: [wave][val][lane], lane-stride-1, conflict-free
    if (wvu > 0) {
        red[wvu][0][lane] = numA;  red[wvu][1][lane] = seA;
        red[wvu][2][lane] = numB;  red[wvu][3][lane] = seB;
    }
    __syncthreads();
    if (wvu == 0) {
        #pragma unroll
        for (int w2 = 1; w2 < 4; ++w2) {
            numA += red[w2][0][lane];  seA += red[w2][1][lane];
            numB += red[w2][2][lane];  seB += red[w2][3][lane];
        }
        float sfA = 0.f, sfB = 0.f;
        #pragma unroll
        for (int j = 0; j < 5; ++j) { sfA += fA[j]; sfB += fB[j]; }
        v2f sg2A = GA[0], sg2B = GB[0];
        #pragma unroll
        for (int p = 1; p < 10; ++p) { sg2A += GA[p]; sg2B += GB[p]; }
        float sgA = sg2A.x + sg2A.y, sgB = sg2B.x + sg2B.y;
        if (vA) out[pA] = numA / (seA * sfA * sgA);
        if (vB) out[pB] = numB / (seB * sfB * sgB);
    }
}

extern "C" void kernel_launch(void* const* d_in, const int* in_sizes, int n_in,
                              void* d_out, int out_size, void* d_ws, size_t ws_size,
                              hipStream_t stream) {
    const float* x       = (const float*)d_in[0];   // (N,3)
    const float* centers = (const float*)d_in[1];   // (C,3) — separable grid
    const float* beta    = (const float*)d_in[2];   // (C,) — constant
    const float* lin_w   = (const float*)d_in[3];   // (1,C)
    float* out = (float*)d_out;                     // (N,1) fp32

    int n = in_sizes[0] / 3;                        // 131072

    int main_blocks = (n + 127) / 128;              // 128 points per block
    rbf_fused<<<main_blocks, 256, 0, stream>>>(x, centers, beta, lin_w, out, n);
}